// Round 6
// baseline (1050.484 us; speedup 1.0000x reference)
//
#include <hip/hip_runtime.h>

#define N_NODES 50000
#define N_EDGES 1000000
#define NB      128         // edge chunks
#define CHUNK   7813        // 128*7813 = 1,000,064 >= E
#define NQ      8           // node ranges per chunk (blockIdx.y)
#define QN      6256        // words per range (16B-aligned); 8*6256 = 50048 >= N
#define NBLK2   196         // ceil(50000/256)

// ---- ws layout (bytes) ----
// part[NB][50000] uint (25.6 MB) lives at 0 and is DEAD after k_fill2;
// xr[50000][9][64] float (115.2 MB) reuses offset 0 after the build.
#define A_PART    0
#define A_XR      0
#define A_DEGP    115200000  // uint[50000] packed: deg_in<<16 | deg_out
#define A_ROWPTR  115400000  // int[50001]
#define A_BSUM    115600128  // int[196]
#define A_BBASE   115601024  // int[196]
#define A_CSR     115601920  // int2[1e6]: (src*9+etype, src)
#define A_HS      123601920  // float[50000*64]
#define A_WALL    136401920  // float[9*64*64]  (ends 136,549,376)

typedef unsigned int uint32;

// K0: Wall[r][i][o] = sum_b comp[r][b]*basis[b][i][o]; Wall[8] = loop_weight
__global__ void k_wall(const float* __restrict__ comp, const float* __restrict__ basis,
                       const float* __restrict__ loopw, float* __restrict__ Wall) {
    int idx = blockIdx.x * 256 + threadIdx.x;
    if (idx >= 9 * 4096) return;
    int r = idx >> 12, io = idx & 4095;
    float acc;
    if (r < 8) {
        acc = 0.f;
        #pragma unroll
        for (int b = 0; b < 30; ++b) acc += comp[r * 30 + b] * basis[b * 4096 + io];
    } else {
        acc = loopw[io];
    }
    Wall[idx] = acc;
}

// K1: per-(chunk, node-range) packed histogram via LDS atomics.
// part[b][v] = (in_count<<16) | out_count for chunk b.
__global__ __launch_bounds__(256) void k_hist2(const int* __restrict__ ei,
                                               uint32* __restrict__ part) {
    __shared__ __align__(16) uint32 h[QN];
    int t = threadIdx.x, b = blockIdx.x, q = blockIdx.y;
    int lo = q * QN;
    int nq = N_NODES - lo; if (nq > QN) nq = QN;
    int4* h4 = (int4*)h;
    for (int i = t; i < QN / 4; i += 256) h4[i] = make_int4(0, 0, 0, 0);
    __syncthreads();
    int e0 = b * CHUNK, e1 = e0 + CHUNK;
    if (e1 > N_EDGES) e1 = N_EDGES;
    for (int e = e0 + t; e < e1; e += 256) {
        int s = ei[e], d = ei[N_EDGES + e];
        unsigned rs = (unsigned)(s - lo), rd = (unsigned)(d - lo);
        if (rs < (unsigned)QN) atomicAdd(&h[rs], 1u);
        if (rd < (unsigned)QN) atomicAdd(&h[rd], 0x10000u);
    }
    __syncthreads();
    int4* d4 = (int4*)(part + b * N_NODES + lo);
    const int4* s4 = (const int4*)h;
    for (int i = t; i < nq / 4; i += 256) d4[i] = s4[i];
}

// K2: degp[v] = sum_b part[b][v]; block sums of deg_in for the scan.
__global__ __launch_bounds__(256) void k_merge(const uint32* __restrict__ part,
                                               uint32* __restrict__ degp,
                                               int* __restrict__ bsum) {
    int t = threadIdx.x, v = blockIdx.x * 256 + t;
    uint32 s = 0;
    if (v < N_NODES) {
        #pragma unroll 8
        for (int b = 0; b < NB; ++b) s += part[b * N_NODES + v];
        degp[v] = s;
    }
    int din = (int)(s >> 16);
    int r = din;
    #pragma unroll
    for (int d = 1; d < 64; d <<= 1) r += __shfl_xor(r, d);
    __shared__ int wsum[4];
    int lane = t & 63, wid = t >> 6;
    if (lane == 0) wsum[wid] = r;
    __syncthreads();
    if (t == 0) bsum[blockIdx.x] = wsum[0] + wsum[1] + wsum[2] + wsum[3];
}

// K3: exclusive scan of 196 block sums (single block).
__global__ void k_scanb(const int* __restrict__ bsum, int* __restrict__ bbase) {
    int t = threadIdx.x;
    int v = (t < NBLK2) ? bsum[t] : 0;
    int lane = t & 63, wid = t >> 6;
    int x = v;
    #pragma unroll
    for (int d = 1; d < 64; d <<= 1) {
        int y = __shfl_up(x, d);
        if (lane >= d) x += y;
    }
    __shared__ int wsum[4];
    if (lane == 63) wsum[wid] = x;
    __syncthreads();
    int base = 0;
    for (int w = 0; w < wid; ++w) base += wsum[w];
    if (t < NBLK2) bbase[t] = base + x - v;
}

// K4: rowptr[v]; convert part[b][v] in-place into fill offsets.
__global__ __launch_bounds__(256) void k_base(uint32* __restrict__ part,
                                              const uint32* __restrict__ degp,
                                              const int* __restrict__ bbase,
                                              int* __restrict__ rowptr) {
    int t = threadIdx.x, v = blockIdx.x * 256 + t;
    int din = (v < N_NODES) ? (int)(degp[v] >> 16) : 0;
    int lane = t & 63, wid = t >> 6;
    int x = din;
    #pragma unroll
    for (int d = 1; d < 64; d <<= 1) {
        int y = __shfl_up(x, d);
        if (lane >= d) x += y;
    }
    __shared__ int wsum[4];
    if (lane == 63) wsum[wid] = x;
    __syncthreads();
    int base = bbase[blockIdx.x];
    for (int w = 0; w < wid; ++w) base += wsum[w];
    int start = base + x - din;
    if (v < N_NODES) {
        rowptr[v] = start;
        if (v == N_NODES - 1) rowptr[N_NODES] = start + din;
        uint32 run = (uint32)start;
        for (int b = 0; b < NB; ++b) {
            uint32 p = part[b * N_NODES + v];
            part[b * N_NODES + v] = run;
            run += (p >> 16);
        }
    }
}

// K5: scatter edges into CSR slots; LDS cursors seeded from fillbase.
__global__ __launch_bounds__(256) void k_fill2(const int* __restrict__ ei,
                                               const int* __restrict__ etype,
                                               const uint32* __restrict__ fillbase,
                                               int2* __restrict__ csr) {
    __shared__ __align__(16) uint32 cur[QN];
    int t = threadIdx.x, b = blockIdx.x, q = blockIdx.y;
    int lo = q * QN;
    int nq = N_NODES - lo; if (nq > QN) nq = QN;
    const int4* s4 = (const int4*)(fillbase + b * N_NODES + lo);
    int4* c4 = (int4*)cur;
    for (int i = t; i < nq / 4; i += 256) c4[i] = s4[i];
    __syncthreads();
    int e0 = b * CHUNK, e1 = e0 + CHUNK;
    if (e1 > N_EDGES) e1 = N_EDGES;
    for (int e = e0 + t; e < e1; e += 256) {
        int d = ei[N_EDGES + e];
        unsigned rd = (unsigned)(d - lo);
        if (rd < (unsigned)QN) {
            int s = ei[e], ty = etype[e];
            uint32 pos = atomicAdd(&cur[rd], 1u);
            csr[pos] = make_int2(s * 9 + ty, s);
        }
    }
}

// K6 v6: xr[n][r][64] = x[n][:] @ Wall[r].
// v5 geometry (256-node tile, 4 phases of 16k, LDS = At[16][256] 16 KB +
// Wt[16][64] 4 KB = 20480 B -> 8 blocks/CU LDS-capacity), plus the register
// controls v5 lacked: __launch_bounds__(256,6) caps VGPR at ~85 (6 blocks/CU),
// and #pragma unroll 1 on the phase loop stops the cross-phase software
// pipelining that inflated v5 to 136 VGPR / 10% occupancy / 107 us.
// v3 ran this same inner loop in 72 VGPR, so 85 fits without spill.
// Swizzle: element (k,n) at At[k*256 + (((n>>2)^(k&7))<<2 | (n&3))]:
// b128 reads ~2-way (free), transpose staging writes ~2-way.
__global__ __launch_bounds__(256, 6) void k_xr(const float* __restrict__ x,
                                               const float* __restrict__ Wall,
                                               float* __restrict__ xr) {
    __shared__ __align__(16) float At[16 * 256];   // 16 KB
    __shared__ __align__(16) float Wt[16 * 64];    // 4 KB
    int t = threadIdx.x;
    int n0 = blockIdx.x * 256;
    int r = blockIdx.y;
    int og = t & 7, ng = t >> 3;        // o = og*8 .. +7, nodes = n0 + ng*8 .. +7
    float acc[8][8];
    #pragma unroll
    for (int i = 0; i < 8; ++i)
        #pragma unroll
        for (int j = 0; j < 8; ++j) acc[i][j] = 0.f;

    #pragma unroll 1
    for (int ph = 0; ph < 4; ++ph) {
        if (ph) __syncthreads();   // all waves done reading previous tile
        // stage A transposed+swizzled: 256 nodes x 16 k
        #pragma unroll
        for (int j = 0; j < 4; ++j) {
            int f4 = t + j * 256;          // float4 index < 1024
            int n = f4 >> 2, k4 = f4 & 3;  // 4 float4 per 16-k node row
            float4 v = make_float4(0.f, 0.f, 0.f, 0.f);
            if (n0 + n < N_NODES)
                v = *(const float4*)&x[(n0 + n) * 64 + ph * 16 + k4 * 4];
            int sl = n >> 2, nl = n & 3, kb = k4 * 4;
            At[(kb + 0) * 256 + (((sl ^ ((kb + 0) & 7)) << 2) | nl)] = v.x;
            At[(kb + 1) * 256 + (((sl ^ ((kb + 1) & 7)) << 2) | nl)] = v.y;
            At[(kb + 2) * 256 + (((sl ^ ((kb + 2) & 7)) << 2) | nl)] = v.z;
            At[(kb + 3) * 256 + (((sl ^ ((kb + 3) & 7)) << 2) | nl)] = v.w;
        }
        // stage W (linear float4 copy, conflict-free): 16x64 = 1024 floats
        *(float4*)&Wt[t * 4] = *(const float4*)&Wall[r * 4096 + ph * 1024 + t * 4];
        __syncthreads();
        #pragma unroll
        for (int k = 0; k < 16; ++k) {
            int c = k & 7;
            float4 aA = *(const float4*)&At[k * 256 + (((2 * ng) ^ c) << 2)];
            float4 aB = *(const float4*)&At[k * 256 + (((2 * ng + 1) ^ c) << 2)];
            float4 w0 = *(const float4*)&Wt[k * 64 + og * 8];
            float4 w1 = *(const float4*)&Wt[k * 64 + og * 8 + 4];
            float a_[8] = {aA.x, aA.y, aA.z, aA.w, aB.x, aB.y, aB.z, aB.w};
            float w_[8] = {w0.x, w0.y, w0.z, w0.w, w1.x, w1.y, w1.z, w1.w};
            #pragma unroll
            for (int i = 0; i < 8; ++i)
                #pragma unroll
                for (int j = 0; j < 8; ++j) acc[i][j] += a_[i] * w_[j];
        }
    }
    #pragma unroll
    for (int i = 0; i < 8; ++i) {
        int n = n0 + ng * 8 + i;
        if (n < N_NODES) {
            *(float4*)&xr[n * 576 + r * 64 + og * 8] =
                make_float4(acc[i][0], acc[i][1], acc[i][2], acc[i][3]);
            *(float4*)&xr[n * 576 + r * 64 + og * 8 + 4] =
                make_float4(acc[i][4], acc[i][5], acc[i][6], acc[i][7]);
        }
    }
}

// K7: hs[v] = (sum_in xr[csr.x] + xr[v*9+8] + bias1) * rsqrt(deg_out[v])
__global__ __launch_bounds__(256) void k_agg1(const float* __restrict__ xr,
                                              const int2* __restrict__ csr,
                                              const int* __restrict__ rowptr,
                                              const uint32* __restrict__ degp,
                                              const float* __restrict__ bias1,
                                              float* __restrict__ hs) {
    int wid = threadIdx.x >> 6, lane = threadIdx.x & 63;
    int v = blockIdx.x * 4 + wid;
    if (v >= N_NODES) return;
    float acc = xr[(v * 9 + 8) * 64 + lane] + bias1[lane];
    int j = rowptr[v], end = rowptr[v + 1];
    for (; j + 4 <= end; j += 4) {
        int r0 = csr[j].x, r1 = csr[j + 1].x, r2 = csr[j + 2].x, r3 = csr[j + 3].x;
        float a0 = xr[r0 * 64 + lane], a1 = xr[r1 * 64 + lane];
        float a2 = xr[r2 * 64 + lane], a3 = xr[r3 * 64 + lane];
        acc += a0; acc += a1; acc += a2; acc += a3;
    }
    for (; j < end; ++j) acc += xr[csr[j].x * 64 + lane];
    float dg = (float)(degp[v] & 0xffffu);
    if (dg < 1.f) dg = 1.f;
    hs[v * 64 + lane] = acc * rsqrtf(dg);
}

// K8: out[v] = (rsqrt(deg_in[v]) * sum_in hs[csr.y]) @ W2 + bias2
__global__ __launch_bounds__(256) void k_layer2(const float* __restrict__ hs,
                                                const int2* __restrict__ csr,
                                                const int* __restrict__ rowptr,
                                                const uint32* __restrict__ degp,
                                                const float* __restrict__ w2,
                                                const float* __restrict__ bias2,
                                                float* __restrict__ out) {
    __shared__ __align__(16) float W2s[64 * 64];
    __shared__ __align__(16) float ys[4 * 64];
    int t = threadIdx.x;
    #pragma unroll
    for (int j = 0; j < 16; ++j) W2s[t + j * 256] = w2[t + j * 256];
    int wid = t >> 6, lane = t & 63;
    int v = blockIdx.x * 4 + wid;
    float acc = 0.f;
    int j = 0, end = 0;
    if (v < N_NODES) { j = rowptr[v]; end = rowptr[v + 1]; }
    for (; j + 4 <= end; j += 4) {
        int r0 = csr[j].y, r1 = csr[j + 1].y, r2 = csr[j + 2].y, r3 = csr[j + 3].y;
        float a0 = hs[r0 * 64 + lane], a1 = hs[r1 * 64 + lane];
        float a2 = hs[r2 * 64 + lane], a3 = hs[r3 * 64 + lane];
        acc += a0; acc += a1; acc += a2; acc += a3;
    }
    for (; j < end; ++j) acc += hs[csr[j].y * 64 + lane];
    if (v < N_NODES) {
        float dg = (float)(degp[v] >> 16);
        if (dg < 1.f) dg = 1.f;
        ys[wid * 64 + lane] = acc * rsqrtf(dg);
    }
    __syncthreads();
    if (v >= N_NODES) return;
    float o = bias2[lane];
    const float* yrow = &ys[wid * 64];
    #pragma unroll 4
    for (int k = 0; k < 64; ++k) o += yrow[k] * W2s[k * 64 + lane];
    out[v * 64 + lane] = o;
}

extern "C" void kernel_launch(void* const* d_in, const int* in_sizes, int n_in,
                              void* d_out, int out_size, void* d_ws, size_t ws_size,
                              hipStream_t stream) {
    const float* x      = (const float*)d_in[0];
    const int*   ei     = (const int*)d_in[1];   // [2E]: src then dst
    const int*   etype  = (const int*)d_in[3];
    const float* basis  = (const float*)d_in[4];
    const float* comp   = (const float*)d_in[5];
    const float* loopw  = (const float*)d_in[6];
    const float* bias1  = (const float*)d_in[7];
    const float* w2     = (const float*)d_in[8];
    const float* bias2  = (const float*)d_in[9];
    float* out = (float*)d_out;

    char* ws = (char*)d_ws;
    uint32* part   = (uint32*)(ws + A_PART);
    float*  xr     = (float*)(ws + A_XR);      // aliases part; written after fill
    uint32* degp   = (uint32*)(ws + A_DEGP);
    int*    rowptr = (int*)(ws + A_ROWPTR);
    int*    bsum   = (int*)(ws + A_BSUM);
    int*    bbase  = (int*)(ws + A_BBASE);
    int2*   csr    = (int2*)(ws + A_CSR);
    float*  hs     = (float*)(ws + A_HS);
    float*  Wall   = (float*)(ws + A_WALL);

    k_wall<<<144, 256, 0, stream>>>(comp, basis, loopw, Wall);
    k_hist2<<<dim3(NB, NQ), 256, 0, stream>>>(ei, part);
    k_merge<<<NBLK2, 256, 0, stream>>>(part, degp, bsum);
    k_scanb<<<1, 256, 0, stream>>>(bsum, bbase);
    k_base<<<NBLK2, 256, 0, stream>>>(part, degp, bbase, rowptr);
    k_fill2<<<dim3(NB, NQ), 256, 0, stream>>>(ei, etype, part, csr);
    k_xr<<<dim3((N_NODES + 255) / 256, 9), 256, 0, stream>>>(x, Wall, xr);
    k_agg1<<<N_NODES / 4, 256, 0, stream>>>(xr, csr, rowptr, degp, bias1, hs);
    k_layer2<<<N_NODES / 4, 256, 0, stream>>>(hs, csr, rowptr, degp, w2, bias2, out);
}

// Round 7
// 310.090 us; speedup vs baseline: 3.3877x; 3.3877x over previous
//
#include <hip/hip_runtime.h>

#define N_NODES 50000
#define N_EDGES 1000000
#define NB      128         // edge chunks
#define CHUNK   7813        // 128*7813 = 1,000,064 >= E
#define NQ      8           // node ranges per chunk (blockIdx.y)
#define QN      6256        // words per range (16B-aligned); 8*6256 = 50048 >= N
#define NBLK2   196         // ceil(50000/256)

// ---- ws layout (bytes) ----
// part[NB][50000] uint (25.6 MB) lives at 0 and is DEAD after k_fill2;
// xr[50000][9][64] float (115.2 MB) reuses offset 0 after the build;
// y2[50000][64] float (12.8 MB) reuses offset 0 after k_agg1 consumes xr.
#define A_PART    0
#define A_XR      0
#define A_Y2      0
#define A_DEGP    115200000  // uint[50000] packed: deg_in<<16 | deg_out
#define A_ROWPTR  115400000  // int[50001]
#define A_BSUM    115600128  // int[196]
#define A_BBASE   115601024  // int[196]
#define A_CSR     115601920  // int2[1e6]: (src*9+etype, src)
#define A_HS      123601920  // float[50000*64]
#define A_WALL    136401920  // float[9*64*64]  (ends 136,549,376)

typedef unsigned int uint32;

// K0: Wall[r][i][o] = sum_b comp[r][b]*basis[b][i][o]; Wall[8] = loop_weight
__global__ void k_wall(const float* __restrict__ comp, const float* __restrict__ basis,
                       const float* __restrict__ loopw, float* __restrict__ Wall) {
    int idx = blockIdx.x * 256 + threadIdx.x;
    if (idx >= 9 * 4096) return;
    int r = idx >> 12, io = idx & 4095;
    float acc;
    if (r < 8) {
        acc = 0.f;
        #pragma unroll
        for (int b = 0; b < 30; ++b) acc += comp[r * 30 + b] * basis[b * 4096 + io];
    } else {
        acc = loopw[io];
    }
    Wall[idx] = acc;
}

// K1: per-(chunk, node-range) packed histogram via LDS atomics.
// part[b][v] = (in_count<<16) | out_count for chunk b.
__global__ __launch_bounds__(256) void k_hist2(const int* __restrict__ ei,
                                               uint32* __restrict__ part) {
    __shared__ __align__(16) uint32 h[QN];
    int t = threadIdx.x, b = blockIdx.x, q = blockIdx.y;
    int lo = q * QN;
    int nq = N_NODES - lo; if (nq > QN) nq = QN;
    int4* h4 = (int4*)h;
    for (int i = t; i < QN / 4; i += 256) h4[i] = make_int4(0, 0, 0, 0);
    __syncthreads();
    int e0 = b * CHUNK, e1 = e0 + CHUNK;
    if (e1 > N_EDGES) e1 = N_EDGES;
    for (int e = e0 + t; e < e1; e += 256) {
        int s = ei[e], d = ei[N_EDGES + e];
        unsigned rs = (unsigned)(s - lo), rd = (unsigned)(d - lo);
        if (rs < (unsigned)QN) atomicAdd(&h[rs], 1u);
        if (rd < (unsigned)QN) atomicAdd(&h[rd], 0x10000u);
    }
    __syncthreads();
    int4* d4 = (int4*)(part + b * N_NODES + lo);
    const int4* s4 = (const int4*)h;
    for (int i = t; i < nq / 4; i += 256) d4[i] = s4[i];
}

// K2: degp[v] = sum_b part[b][v]; block sums of deg_in for the scan.
__global__ __launch_bounds__(256) void k_merge(const uint32* __restrict__ part,
                                               uint32* __restrict__ degp,
                                               int* __restrict__ bsum) {
    int t = threadIdx.x, v = blockIdx.x * 256 + t;
    uint32 s = 0;
    if (v < N_NODES) {
        #pragma unroll 8
        for (int b = 0; b < NB; ++b) s += part[b * N_NODES + v];
        degp[v] = s;
    }
    int din = (int)(s >> 16);
    int r = din;
    #pragma unroll
    for (int d = 1; d < 64; d <<= 1) r += __shfl_xor(r, d);
    __shared__ int wsum[4];
    int lane = t & 63, wid = t >> 6;
    if (lane == 0) wsum[wid] = r;
    __syncthreads();
    if (t == 0) bsum[blockIdx.x] = wsum[0] + wsum[1] + wsum[2] + wsum[3];
}

// K3: exclusive scan of 196 block sums (single block).
__global__ void k_scanb(const int* __restrict__ bsum, int* __restrict__ bbase) {
    int t = threadIdx.x;
    int v = (t < NBLK2) ? bsum[t] : 0;
    int lane = t & 63, wid = t >> 6;
    int x = v;
    #pragma unroll
    for (int d = 1; d < 64; d <<= 1) {
        int y = __shfl_up(x, d);
        if (lane >= d) x += y;
    }
    __shared__ int wsum[4];
    if (lane == 63) wsum[wid] = x;
    __syncthreads();
    int base = 0;
    for (int w = 0; w < wid; ++w) base += wsum[w];
    if (t < NBLK2) bbase[t] = base + x - v;
}

// K4: rowptr[v]; convert part[b][v] in-place into fill offsets.
__global__ __launch_bounds__(256) void k_base(uint32* __restrict__ part,
                                              const uint32* __restrict__ degp,
                                              const int* __restrict__ bbase,
                                              int* __restrict__ rowptr) {
    int t = threadIdx.x, v = blockIdx.x * 256 + t;
    int din = (v < N_NODES) ? (int)(degp[v] >> 16) : 0;
    int lane = t & 63, wid = t >> 6;
    int x = din;
    #pragma unroll
    for (int d = 1; d < 64; d <<= 1) {
        int y = __shfl_up(x, d);
        if (lane >= d) x += y;
    }
    __shared__ int wsum[4];
    if (lane == 63) wsum[wid] = x;
    __syncthreads();
    int base = bbase[blockIdx.x];
    for (int w = 0; w < wid; ++w) base += wsum[w];
    int start = base + x - din;
    if (v < N_NODES) {
        rowptr[v] = start;
        if (v == N_NODES - 1) rowptr[N_NODES] = start + din;
        uint32 run = (uint32)start;
        for (int b = 0; b < NB; ++b) {
            uint32 p = part[b * N_NODES + v];
            part[b * N_NODES + v] = run;
            run += (p >> 16);
        }
    }
}

// K5: scatter edges into CSR slots; LDS cursors seeded from fillbase.
__global__ __launch_bounds__(256) void k_fill2(const int* __restrict__ ei,
                                               const int* __restrict__ etype,
                                               const uint32* __restrict__ fillbase,
                                               int2* __restrict__ csr) {
    __shared__ __align__(16) uint32 cur[QN];
    int t = threadIdx.x, b = blockIdx.x, q = blockIdx.y;
    int lo = q * QN;
    int nq = N_NODES - lo; if (nq > QN) nq = QN;
    const int4* s4 = (const int4*)(fillbase + b * N_NODES + lo);
    int4* c4 = (int4*)cur;
    for (int i = t; i < nq / 4; i += 256) c4[i] = s4[i];
    __syncthreads();
    int e0 = b * CHUNK, e1 = e0 + CHUNK;
    if (e1 > N_EDGES) e1 = N_EDGES;
    for (int e = e0 + t; e < e1; e += 256) {
        int d = ei[N_EDGES + e];
        unsigned rd = (unsigned)(d - lo);
        if (rd < (unsigned)QN) {
            int s = ei[e], ty = etype[e];
            uint32 pos = atomicAdd(&cur[rd], 1u);
            csr[pos] = make_int2(s * 9 + ty, s);
        }
    }
}

// K6 (= proven v3, 69 us): xr[n][r][64] = x[n][:] @ Wall[r].
// 256 nodes x 64 outs per block, 256 threads, 8x8 per-thread tile, K split
// into two 32-wide phases: LDS = At[32][256] 32 KB + Wt[32][64] 8 KB = 40 KB.
// DO NOT touch occupancy: 4-phase split inflated VGPR to 136 (107 us, v5);
// launch_bounds(256,6) forced 40 VGPR and spilled acc to scratch (785 us, v6).
__global__ __launch_bounds__(256) void k_xr(const float* __restrict__ x,
                                            const float* __restrict__ Wall,
                                            float* __restrict__ xr) {
    __shared__ __align__(16) float At[32 * 256];   // 32 KB
    __shared__ __align__(16) float Wt[32 * 64];    // 8 KB
    int t = threadIdx.x;
    int n0 = blockIdx.x * 256;
    int r = blockIdx.y;
    int og = t & 7, ng = t >> 3;        // o = og*8 .. +7, nodes = n0 + ng*8 .. +7
    float acc[8][8];
    #pragma unroll
    for (int i = 0; i < 8; ++i)
        #pragma unroll
        for (int j = 0; j < 8; ++j) acc[i][j] = 0.f;

    #pragma unroll
    for (int ph = 0; ph < 2; ++ph) {
        if (ph) __syncthreads();   // all waves done reading phase-0 tiles
        // stage A transposed+swizzled: 256 nodes x 32 k
        #pragma unroll
        for (int j = 0; j < 8; ++j) {
            int f4 = t + j * 256;          // float4 index, < 2048
            int n = f4 >> 3, k4 = f4 & 7;  // 8 float4 per 32-k node row
            float4 v = make_float4(0.f, 0.f, 0.f, 0.f);
            if (n0 + n < N_NODES)
                v = *(const float4*)&x[(n0 + n) * 64 + ph * 32 + k4 * 4];
            int sl = n >> 2, nl = n & 3, kb = k4 * 4;
            At[(kb + 0) * 256 + (((sl ^ ((kb + 0) & 7)) << 2) | nl)] = v.x;
            At[(kb + 1) * 256 + (((sl ^ ((kb + 1) & 7)) << 2) | nl)] = v.y;
            At[(kb + 2) * 256 + (((sl ^ ((kb + 2) & 7)) << 2) | nl)] = v.z;
            At[(kb + 3) * 256 + (((sl ^ ((kb + 3) & 7)) << 2) | nl)] = v.w;
        }
        // stage W (linear copy, conflict-free)
        #pragma unroll
        for (int j = 0; j < 8; ++j) {
            int f = t + j * 256;
            Wt[f] = Wall[r * 4096 + ph * 2048 + f];
        }
        __syncthreads();
        #pragma unroll 4
        for (int k = 0; k < 32; ++k) {
            int c = k & 7;
            float4 aA = *(const float4*)&At[k * 256 + (((2 * ng) ^ c) << 2)];
            float4 aB = *(const float4*)&At[k * 256 + (((2 * ng + 1) ^ c) << 2)];
            float4 w0 = *(const float4*)&Wt[k * 64 + og * 8];
            float4 w1 = *(const float4*)&Wt[k * 64 + og * 8 + 4];
            float a_[8] = {aA.x, aA.y, aA.z, aA.w, aB.x, aB.y, aB.z, aB.w};
            float w_[8] = {w0.x, w0.y, w0.z, w0.w, w1.x, w1.y, w1.z, w1.w};
            #pragma unroll
            for (int i = 0; i < 8; ++i)
                #pragma unroll
                for (int j = 0; j < 8; ++j) acc[i][j] += a_[i] * w_[j];
        }
    }
    #pragma unroll
    for (int i = 0; i < 8; ++i) {
        int n = n0 + ng * 8 + i;
        if (n < N_NODES) {
            *(float4*)&xr[n * 576 + r * 64 + og * 8] =
                make_float4(acc[i][0], acc[i][1], acc[i][2], acc[i][3]);
            *(float4*)&xr[n * 576 + r * 64 + og * 8 + 4] =
                make_float4(acc[i][4], acc[i][5], acc[i][6], acc[i][7]);
        }
    }
}

// K7: hs[v] = (sum_in xr[csr.x] + xr[v*9+8] + bias1) * rsqrt(deg_out[v])
__global__ __launch_bounds__(256) void k_agg1(const float* __restrict__ xr,
                                              const int2* __restrict__ csr,
                                              const int* __restrict__ rowptr,
                                              const uint32* __restrict__ degp,
                                              const float* __restrict__ bias1,
                                              float* __restrict__ hs) {
    int wid = threadIdx.x >> 6, lane = threadIdx.x & 63;
    int v = blockIdx.x * 4 + wid;
    if (v >= N_NODES) return;
    float acc = xr[(v * 9 + 8) * 64 + lane] + bias1[lane];
    int j = rowptr[v], end = rowptr[v + 1];
    for (; j + 4 <= end; j += 4) {
        int r0 = csr[j].x, r1 = csr[j + 1].x, r2 = csr[j + 2].x, r3 = csr[j + 3].x;
        float a0 = xr[r0 * 64 + lane], a1 = xr[r1 * 64 + lane];
        float a2 = xr[r2 * 64 + lane], a3 = xr[r3 * 64 + lane];
        acc += a0; acc += a1; acc += a2; acc += a3;
    }
    for (; j < end; ++j) acc += xr[csr[j].x * 64 + lane];
    float dg = (float)(degp[v] & 0xffffu);
    if (dg < 1.f) dg = 1.f;
    hs[v * 64 + lane] = acc * rsqrtf(dg);
}

// K8a: y2[v] = rsqrt(deg_in[v]) * sum_in hs[csr.y] — gather only, no GEMV,
// no LDS, no barrier. y2 lives at ws offset 0 (xr is dead after k_agg1).
__global__ __launch_bounds__(256) void k_agg2(const float* __restrict__ hs,
                                              const int2* __restrict__ csr,
                                              const int* __restrict__ rowptr,
                                              const uint32* __restrict__ degp,
                                              float* __restrict__ y2) {
    int wid = threadIdx.x >> 6, lane = threadIdx.x & 63;
    int v = blockIdx.x * 4 + wid;
    if (v >= N_NODES) return;
    float acc = 0.f;
    int j = rowptr[v], end = rowptr[v + 1];
    for (; j + 4 <= end; j += 4) {
        int r0 = csr[j].y, r1 = csr[j + 1].y, r2 = csr[j + 2].y, r3 = csr[j + 3].y;
        float a0 = hs[r0 * 64 + lane], a1 = hs[r1 * 64 + lane];
        float a2 = hs[r2 * 64 + lane], a3 = hs[r3 * 64 + lane];
        acc += a0; acc += a1; acc += a2; acc += a3;
    }
    for (; j < end; ++j) acc += hs[csr[j].y * 64 + lane];
    float dg = (float)(degp[v] >> 16);
    if (dg < 1.f) dg = 1.f;
    y2[v * 64 + lane] = acc * rsqrtf(dg);
}

// K8b: out = y2 @ w2 + bias2 — batched tiled GEMM (v3-k_xr structure, one
// "relation"). 50000x64x64 = 0.4 GFLOP; replaces the per-node LDS-bound GEMV
// that k_layer2 ran serially after every gather.
__global__ __launch_bounds__(256) void k_gemm2(const float* __restrict__ y2,
                                               const float* __restrict__ w2,
                                               const float* __restrict__ bias2,
                                               float* __restrict__ out) {
    __shared__ __align__(16) float At[32 * 256];   // 32 KB
    __shared__ __align__(16) float Wt[32 * 64];    // 8 KB
    int t = threadIdx.x;
    int n0 = blockIdx.x * 256;
    int og = t & 7, ng = t >> 3;
    float acc[8][8];
    #pragma unroll
    for (int i = 0; i < 8; ++i)
        #pragma unroll
        for (int j = 0; j < 8; ++j) acc[i][j] = 0.f;

    #pragma unroll
    for (int ph = 0; ph < 2; ++ph) {
        if (ph) __syncthreads();
        #pragma unroll
        for (int j = 0; j < 8; ++j) {
            int f4 = t + j * 256;
            int n = f4 >> 3, k4 = f4 & 7;
            float4 v = make_float4(0.f, 0.f, 0.f, 0.f);
            if (n0 + n < N_NODES)
                v = *(const float4*)&y2[(n0 + n) * 64 + ph * 32 + k4 * 4];
            int sl = n >> 2, nl = n & 3, kb = k4 * 4;
            At[(kb + 0) * 256 + (((sl ^ ((kb + 0) & 7)) << 2) | nl)] = v.x;
            At[(kb + 1) * 256 + (((sl ^ ((kb + 1) & 7)) << 2) | nl)] = v.y;
            At[(kb + 2) * 256 + (((sl ^ ((kb + 2) & 7)) << 2) | nl)] = v.z;
            At[(kb + 3) * 256 + (((sl ^ ((kb + 3) & 7)) << 2) | nl)] = v.w;
        }
        #pragma unroll
        for (int j = 0; j < 8; ++j) {
            int f = t + j * 256;
            Wt[f] = w2[ph * 2048 + f];
        }
        __syncthreads();
        #pragma unroll 4
        for (int k = 0; k < 32; ++k) {
            int c = k & 7;
            float4 aA = *(const float4*)&At[k * 256 + (((2 * ng) ^ c) << 2)];
            float4 aB = *(const float4*)&At[k * 256 + (((2 * ng + 1) ^ c) << 2)];
            float4 w0 = *(const float4*)&Wt[k * 64 + og * 8];
            float4 w1 = *(const float4*)&Wt[k * 64 + og * 8 + 4];
            float a_[8] = {aA.x, aA.y, aA.z, aA.w, aB.x, aB.y, aB.z, aB.w};
            float w_[8] = {w0.x, w0.y, w0.z, w0.w, w1.x, w1.y, w1.z, w1.w};
            #pragma unroll
            for (int i = 0; i < 8; ++i)
                #pragma unroll
                for (int j = 0; j < 8; ++j) acc[i][j] += a_[i] * w_[j];
        }
    }
    float4 b0 = *(const float4*)&bias2[og * 8];
    float4 b1 = *(const float4*)&bias2[og * 8 + 4];
    #pragma unroll
    for (int i = 0; i < 8; ++i) {
        int n = n0 + ng * 8 + i;
        if (n < N_NODES) {
            *(float4*)&out[n * 64 + og * 8] =
                make_float4(acc[i][0] + b0.x, acc[i][1] + b0.y,
                            acc[i][2] + b0.z, acc[i][3] + b0.w);
            *(float4*)&out[n * 64 + og * 8 + 4] =
                make_float4(acc[i][4] + b1.x, acc[i][5] + b1.y,
                            acc[i][6] + b1.z, acc[i][7] + b1.w);
        }
    }
}

extern "C" void kernel_launch(void* const* d_in, const int* in_sizes, int n_in,
                              void* d_out, int out_size, void* d_ws, size_t ws_size,
                              hipStream_t stream) {
    const float* x      = (const float*)d_in[0];
    const int*   ei     = (const int*)d_in[1];   // [2E]: src then dst
    const int*   etype  = (const int*)d_in[3];
    const float* basis  = (const float*)d_in[4];
    const float* comp   = (const float*)d_in[5];
    const float* loopw  = (const float*)d_in[6];
    const float* bias1  = (const float*)d_in[7];
    const float* w2     = (const float*)d_in[8];
    const float* bias2  = (const float*)d_in[9];
    float* out = (float*)d_out;

    char* ws = (char*)d_ws;
    uint32* part   = (uint32*)(ws + A_PART);
    float*  xr     = (float*)(ws + A_XR);      // aliases part; written after fill
    float*  y2     = (float*)(ws + A_Y2);      // aliases xr; written after agg1
    uint32* degp   = (uint32*)(ws + A_DEGP);
    int*    rowptr = (int*)(ws + A_ROWPTR);
    int*    bsum   = (int*)(ws + A_BSUM);
    int*    bbase  = (int*)(ws + A_BBASE);
    int2*   csr    = (int2*)(ws + A_CSR);
    float*  hs     = (float*)(ws + A_HS);
    float*  Wall   = (float*)(ws + A_WALL);

    k_wall<<<144, 256, 0, stream>>>(comp, basis, loopw, Wall);
    k_hist2<<<dim3(NB, NQ), 256, 0, stream>>>(ei, part);
    k_merge<<<NBLK2, 256, 0, stream>>>(part, degp, bsum);
    k_scanb<<<1, 256, 0, stream>>>(bsum, bbase);
    k_base<<<NBLK2, 256, 0, stream>>>(part, degp, bbase, rowptr);
    k_fill2<<<dim3(NB, NQ), 256, 0, stream>>>(ei, etype, part, csr);
    k_xr<<<dim3((N_NODES + 255) / 256, 9), 256, 0, stream>>>(x, Wall, xr);
    k_agg1<<<N_NODES / 4, 256, 0, stream>>>(xr, csr, rowptr, degp, bias1, hs);
    k_agg2<<<N_NODES / 4, 256, 0, stream>>>(hs, csr, rowptr, degp, y2);
    k_gemm2<<<(N_NODES + 255) / 256, 256, 0, stream>>>(y2, w2, bias2, out);
}